// Round 16
// baseline (93.627 us; speedup 1.0000x reference)
//
#include <hip/hip_runtime.h>

// Fused KernelWarehouse dynamic conv, round 13 (base: R10/R15, 82us plateau):
//   logits = 1x1 conv -> softmax K=4 -> 3x3 convs -> mixture (dot2 f16 path).
// R5-R15 falsified: TLP, barrier semantics/count, LDS width, fetch volume,
// iteration count. Achieved BW stuck at 4.35 TB/s = 69% of stream ceiling;
// all prior variants issue 160-288B scattered bursts. R16: FULL-WIDTH 8-row
// strips -> every wave staging load = 64 lanes x 16B = 1KB contiguous run
// (the m13 6.3TB/s pattern). No horizontal halo; vertical-only 10/8 staging.
// XCD grouping: b = fid&15 -> all strips of an image pin to one XCD (plane
// slices L2-fit, vertical halo rows shared in-XCD).
// Kept: dot2/half2 pairs, packed weights, CPB=2 LDS dbuf, 2-deep reg
// prefetch, 1 barrier/group, 4-px per-thread strips (R10 shape).

typedef _Float16 half2_t __attribute__((ext_vector_type(2)));
typedef unsigned int uint;

#define HH 256
#define WW 256
#define CH 64
#define PLANE (HH * WW)
#define NT 512                   // threads per block
#define SR 8                     // strip rows
#define ROWS 10                  // staged rows incl. vertical halo
#define NG 32                    // channel pairs (= groups)
#define NC4 64                   // 16B units per row (full width)
#define P 259                    // LDS dword row stride (odd; px p -> dword p+1)
#define BUF_DW (ROWS * P)        // 2590 dwords per buffer (10.4 KB)
#define TU (ROWS * NC4)          // 640 units per group (unit = 4 px x 2 ch)
#define NS 2                     // units per thread (ceil 640/512)

// packed-weight table in d_ws:
//   uint wpk[4][32][9] : half2(w[k][2p][tap], w[k][2p+1][tap])  (1152)
//   uint apk[4][32]    : half2(attn_w[k][2p], attn_w[k][2p+1])  (128)
#define WPK_N 1152
#define APK_OFF 1152

__device__ __forceinline__ uint pkrtz(float a, float b) {
    return __builtin_bit_cast(uint, __builtin_amdgcn_cvt_pkrtz(a, b));
}

__device__ __forceinline__ float dot2(uint a, uint b, float c) {
#if __has_builtin(__builtin_amdgcn_fdot2)
    return __builtin_amdgcn_fdot2(__builtin_bit_cast(half2_t, a),
                                  __builtin_bit_cast(half2_t, b), c, false);
#else
    half2_t ha = __builtin_bit_cast(half2_t, a);
    half2_t hb = __builtin_bit_cast(half2_t, b);
    return c + (float)ha[0] * (float)hb[0] + (float)ha[1] * (float)hb[1];
#endif
}

__global__ void kwdc_pack(const float* __restrict__ weight,
                          const float* __restrict__ attn_w,
                          uint* __restrict__ wsu) {
    int e = blockIdx.x * 256 + threadIdx.x;
    if (e < WPK_N) {
        int k = e / 288, rem = e % 288, pair = rem / 9, tap = rem % 9;
        int c0 = 2 * pair;
        wsu[e] = pkrtz(weight[(k * CH + c0) * 9 + tap],
                       weight[(k * CH + c0 + 1) * 9 + tap]);
    } else if (e < WPK_N + 128) {
        int e2 = e - WPK_N;
        int k = e2 / 32, pair = e2 % 32;
        int c0 = 2 * pair;
        wsu[APK_OFF + e2] = pkrtz(attn_w[k * CH + c0], attn_w[k * CH + c0 + 1]);
    }
}

__global__ __launch_bounds__(NT, 4) void kwdc_main(
    const float* __restrict__ x,       // [B,C,H,W] f32
    const uint*  __restrict__ wsu,     // packed weights (d_ws)
    const float* __restrict__ attn_b,  // [K] f32
    float* __restrict__ out)           // [B,1,H,W] f32
{
    __shared__ uint lds[2][BUF_DW];    // 2 x 10.4 KB

    const int tid = threadIdx.x;

    // decode: b in LOW bits -> blockIdx mod 8 = image mod 8 -> all 32 strips
    // of one image land on (at most) 2 XCDs; vertical neighbors share L2.
    const int fid = blockIdx.x;        // 0..511
    const int b   = fid & 15;          // image
    const int s   = fid >> 4;          // strip 0..31

    const int h0 = s * SR;

    const int tr = tid >> 6;     // 0..7 row in strip
    const int cg = tid & 63;     // col group
    const int wb = cg * 4;       // col base (4-wide strip)

    const float* xb = x + (size_t)b * CH * PLANE;

    // ---- staging metadata (unit = 4 px of channels 2g,2g+1) ----
    // unit i: row = i>>6, col4 = i&63 -> one wave = one full 1KB row run.
    int  s_gofs[NS];
    int  s_lofs[NS];
    bool s_val[NS];
    bool s_act[NS];
#pragma unroll
    for (int q = 0; q < NS; ++q) {
        int i = tid + q * NT;
        bool act = i < TU;
        int col4 = i & 63;
        int row  = i >> 6;
        int gh  = h0 + row - 1;
        s_act[q]  = act;
        s_val[q]  = act && ((unsigned)gh < HH);
        s_gofs[q] = gh * WW + col4 * 4;
        s_lofs[q] = row * P + col4 * 4 + 1;   // px p stored at dword p+1
    }

    struct Unit { float4 a, b; };
    Unit stgA[NS], stgB[NS];           // 2-deep prefetch sets

    auto load_set = [&](int g, Unit* stg) {
#pragma unroll
        for (int q = 0; q < NS; ++q) {
            float4 va = {0.f, 0.f, 0.f, 0.f}, vb = va;
            if (s_val[q]) {
                const float* pa = xb + (size_t)(2 * g) * PLANE + s_gofs[q];
                va = *reinterpret_cast<const float4*>(pa);
                vb = *reinterpret_cast<const float4*>(pa + PLANE);
            }
            stg[q].a = va; stg[q].b = vb;
        }
    };

    auto store_set = [&](const Unit* stg, int buf) {
#pragma unroll
        for (int q = 0; q < NS; ++q) {
            if (s_act[q]) {
                uint* w = &lds[buf][s_lofs[q]];
                w[0] = pkrtz(stg[q].a.x, stg[q].b.x);
                w[1] = pkrtz(stg[q].a.y, stg[q].b.y);
                w[2] = pkrtz(stg[q].a.z, stg[q].b.z);
                w[3] = pkrtz(stg[q].a.w, stg[q].b.w);
            }
        }
    };

    float conv[4][4];
    float logit[4][4];
#pragma unroll
    for (int k = 0; k < 4; ++k)
#pragma unroll
        for (int p = 0; p < 4; ++p) { conv[k][p] = 0.f; logit[k][p] = 0.f; }

    // ---- prologue: stage pair 0; prime 2-deep pipeline ----
    load_set(0, stgA);
    store_set(stgA, 0);
    load_set(1, stgA);   // A holds g1 (stored at iter 0)
    load_set(2, stgB);   // B holds g2 (stored at iter 1)
    __syncthreads();     // buf0 ready

    for (int g = 0; g < NG; ++g) {
        // ---- LDS reads: rows tr..tr+2, px wb-1..wb+4 (dword wb..wb+5) ----
        const uint* tp = &lds[g & 1][tr * P + wb];
        uint rv[3][6];
#pragma unroll
        for (int i = 0; i < 3; ++i)
#pragma unroll
            for (int j = 0; j < 6; ++j)
                rv[i][j] = tp[i * P + j];
        // horizontal image edges: col -1 / col 256 are zero
        if (cg == 0)  { rv[0][0] = 0; rv[1][0] = 0; rv[2][0] = 0; }
        if (cg == 63) { rv[0][5] = 0; rv[1][5] = 0; rv[2][5] = 0; }

        // ---- store set (holds g+1, loaded 2 iters ago); refill with g+3 ----
        if (g + 1 < NG) {
            Unit* setp = (g & 1) ? stgB : stgA;
            store_set(setp, (g + 1) & 1);
            if (g + 3 < NG) load_set(g + 3, setp);
        }

        // ---- packed weights for this pair (uniform -> s_load) ----
        uint w2[4][9];
        uint a2[4];
#pragma unroll
        for (int k = 0; k < 4; ++k) {
            const uint* wq = wsu + k * 288 + g * 9;
#pragma unroll
            for (int t = 0; t < 9; ++t) w2[k][t] = wq[t];
            a2[k] = wsu[APK_OFF + k * 32 + g];
        }

        // ---- compute both channels of the pair via dot2 ----
#pragma unroll
        for (int k = 0; k < 4; ++k) {
#pragma unroll
            for (int p = 0; p < 4; ++p) {
                float acc = conv[k][p];
                acc = dot2(rv[0][p],     w2[k][0], acc);
                acc = dot2(rv[0][p + 1], w2[k][1], acc);
                acc = dot2(rv[0][p + 2], w2[k][2], acc);
                acc = dot2(rv[1][p],     w2[k][3], acc);
                acc = dot2(rv[1][p + 1], w2[k][4], acc);
                acc = dot2(rv[1][p + 2], w2[k][5], acc);
                acc = dot2(rv[2][p],     w2[k][6], acc);
                acc = dot2(rv[2][p + 1], w2[k][7], acc);
                acc = dot2(rv[2][p + 2], w2[k][8], acc);
                conv[k][p] = acc;
                logit[k][p] = dot2(rv[1][p + 1], a2[k], logit[k][p]);
            }
        }
        // one barrier per group: buf[g&1] reads done before iter g+1 rewrites
        // it; buf[(g+1)&1] writes visible for iter g+1's compute
        __syncthreads();
    }

    // ---- epilogue: softmax over K=4 + mixture (all f32) ----
    const float b0 = attn_b[0], b1 = attn_b[1], b2 = attn_b[2], b3 = attn_b[3];
    float4 o;
    float* op = &o.x;
#pragma unroll
    for (int p = 0; p < 4; ++p) {
        float l0 = logit[0][p] + b0;
        float l1 = logit[1][p] + b1;
        float l2 = logit[2][p] + b2;
        float l3 = logit[3][p] + b3;
        float m = fmaxf(fmaxf(l0, l1), fmaxf(l2, l3));
        float e0 = __expf(l0 - m), e1 = __expf(l1 - m);
        float e2 = __expf(l2 - m), e3 = __expf(l3 - m);
        float sden = e0 + e1 + e2 + e3;
        float num = conv[0][p] * e0 + conv[1][p] * e1
                  + conv[2][p] * e2 + conv[3][p] * e3;
        op[p] = num / sden;
    }
    size_t oidx = (size_t)b * PLANE + (size_t)(h0 + tr) * WW + wb;
    *reinterpret_cast<float4*>(out + oidx) = o;
}

extern "C" void kernel_launch(void* const* d_in, const int* in_sizes, int n_in,
                              void* d_out, int out_size, void* d_ws, size_t ws_size,
                              hipStream_t stream) {
    const float* x      = (const float*)d_in[0];
    const float* weight = (const float*)d_in[1];
    const float* attn_w = (const float*)d_in[2];
    const float* attn_b = (const float*)d_in[3];
    float* out = (float*)d_out;
    uint*  wsu = (uint*)d_ws;

    kwdc_pack<<<dim3(5), 256, 0, stream>>>(weight, attn_w, wsu);
    kwdc_main<<<dim3(512), NT, 0, stream>>>(x, wsu, attn_b, out);
}